// Round 5
// baseline (138.202 us; speedup 1.0000x reference)
//
#include <hip/hip_runtime.h>

typedef __bf16 bf16;
typedef __attribute__((ext_vector_type(4))) bf16 bf16x4;
typedef __attribute__((ext_vector_type(8))) bf16 bf16x8;
typedef __attribute__((ext_vector_type(4))) float f32x4;

#define MFMA16(a, b, c) __builtin_amdgcn_mfma_f32_16x16x32_bf16(a, b, c, 0, 0, 0)

constexpr int Bb = 4, Ss = 4096, Ee = 1024, Hh = 128;
constexpr int Mrows = Bb * Ss;  // 16384
constexpr int QB = 128;         // attn q-block
constexpr int NQB = Ss / QB;    // 32

// ---------------------------------------------------------------------------
// Kernel 0: W prep. Transpose W [E,H] f32 -> Wt [3][H][E] bf16.
// grid (E/16, 3), block 256.
// ---------------------------------------------------------------------------
__global__ __launch_bounds__(256) void wprep_kernel(
    const float* __restrict__ Wq, const float* __restrict__ Wk,
    const float* __restrict__ Wv, bf16* __restrict__ Wt)
{
    __shared__ bf16 Sb[16][136];
    const int w = blockIdx.y;
    const float* W = (w == 0) ? Wq : (w == 1) ? Wk : Wv;
    const int k0 = blockIdx.x * 16;
    const int t = threadIdx.x;
    {
        int r = t >> 4, cg = (t & 15) * 8;
        const float4* src = (const float4*)(W + (size_t)(k0 + r) * Hh + cg);
        float4 v0 = src[0], v1 = src[1];
        bf16x4 o0, o1;
        o0[0] = (bf16)v0.x; o0[1] = (bf16)v0.y; o0[2] = (bf16)v0.z; o0[3] = (bf16)v0.w;
        o1[0] = (bf16)v1.x; o1[1] = (bf16)v1.y; o1[2] = (bf16)v1.z; o1[3] = (bf16)v1.w;
        *(bf16x4*)&Sb[r][cg] = o0;
        *(bf16x4*)&Sb[r][cg + 4] = o1;
    }
    __syncthreads();
    {
        int h = t >> 1, kseg = (t & 1) * 8;
        bf16x8 v;
        #pragma unroll
        for (int e = 0; e < 8; ++e) v[e] = Sb[kseg + e][h];
        *(bf16x8*)&Wt[((size_t)w * Hh + h) * Ee + k0 + kseg] = v;
    }
}

// ---------------------------------------------------------------------------
// Kernel 1: fused QKV projection, A-resident design.
// grid (Mrows/32) = 512, block 256 (4 waves). Stage 32 rows x 1024 k of A
// in LDS ONCE; k-loop has no barriers; B-frags read straight from
// L2-resident Wt. Wave w owns output frags F = 6w..6w+5 (F>>3 = proj,
// F&7 = col group). V written transposed: Vtg[b][h][s].
// ---------------------------------------------------------------------------
__global__ __launch_bounds__(256, 2) void proj_kernel(
    const float* __restrict__ embds, const bf16* __restrict__ Wt,
    const float* __restrict__ bq, const float* __restrict__ bk,
    const float* __restrict__ bv,
    bf16* __restrict__ Qb, bf16* __restrict__ Kb, bf16* __restrict__ Vtg)
{
    __shared__ bf16 As[32][1032];   // stride 2064B = 516 dw == 4 mod 32

    const int t = threadIdx.x;
    const int wv = t >> 6, lane = t & 63, lo = lane & 15, hi = lane >> 4;
    const int m0 = blockIdx.x * 32;

    // stage A: thread handles row (t&31), 128 contiguous cols
    {
        int row = t & 31, cb = (t >> 5) * 128;
        const float4* src = (const float4*)(embds + (size_t)(m0 + row) * Ee + cb);
        #pragma unroll
        for (int j = 0; j < 32; ++j) {
            float4 v = src[j];
            bf16x4 o; o[0] = (bf16)v.x; o[1] = (bf16)v.y; o[2] = (bf16)v.z; o[3] = (bf16)v.w;
            *(bf16x4*)&As[row][cb + j * 4] = o;
        }
    }
    __syncthreads();

    // B pointers: 6 frags per wave, compile-time frag offsets
    const bf16* bp0; const bf16* bp1; const bf16* bp2;
    const bf16* bp3; const bf16* bp4; const bf16* bp5;
    {
        const bf16* bb = Wt + (size_t)lo * Ee + hi * 8;
        const int F0 = wv * 6;
        bp0 = bb + (size_t)(((F0 + 0) >> 3) * Hh + ((F0 + 0) & 7) * 16) * Ee;
        bp1 = bb + (size_t)(((F0 + 1) >> 3) * Hh + ((F0 + 1) & 7) * 16) * Ee;
        bp2 = bb + (size_t)(((F0 + 2) >> 3) * Hh + ((F0 + 2) & 7) * 16) * Ee;
        bp3 = bb + (size_t)(((F0 + 3) >> 3) * Hh + ((F0 + 3) & 7) * 16) * Ee;
        bp4 = bb + (size_t)(((F0 + 4) >> 3) * Hh + ((F0 + 4) & 7) * 16) * Ee;
        bp5 = bb + (size_t)(((F0 + 5) >> 3) * Hh + ((F0 + 5) & 7) * 16) * Ee;
    }

    f32x4 acc[2][6];
    #pragma unroll
    for (int rg = 0; rg < 2; ++rg)
        #pragma unroll
        for (int f = 0; f < 6; ++f) acc[rg][f] = f32x4{0.f, 0.f, 0.f, 0.f};

    #pragma unroll 4
    for (int k = 0; k < 32; ++k) {      // K=32 per step
        bf16x8 a0 = *(const bf16x8*)&As[lo][k * 32 + hi * 8];
        bf16x8 a1 = *(const bf16x8*)&As[16 + lo][k * 32 + hi * 8];
        bf16x8 b0 = *(const bf16x8*)(bp0 + k * 32);
        bf16x8 b1 = *(const bf16x8*)(bp1 + k * 32);
        bf16x8 b2 = *(const bf16x8*)(bp2 + k * 32);
        bf16x8 b3 = *(const bf16x8*)(bp3 + k * 32);
        bf16x8 b4 = *(const bf16x8*)(bp4 + k * 32);
        bf16x8 b5 = *(const bf16x8*)(bp5 + k * 32);
        acc[0][0] = MFMA16(a0, b0, acc[0][0]); acc[1][0] = MFMA16(a1, b0, acc[1][0]);
        acc[0][1] = MFMA16(a0, b1, acc[0][1]); acc[1][1] = MFMA16(a1, b1, acc[1][1]);
        acc[0][2] = MFMA16(a0, b2, acc[0][2]); acc[1][2] = MFMA16(a1, b2, acc[1][2]);
        acc[0][3] = MFMA16(a0, b3, acc[0][3]); acc[1][3] = MFMA16(a1, b3, acc[1][3]);
        acc[0][4] = MFMA16(a0, b4, acc[0][4]); acc[1][4] = MFMA16(a1, b4, acc[1][4]);
        acc[0][5] = MFMA16(a0, b5, acc[0][5]); acc[1][5] = MFMA16(a1, b5, acc[1][5]);
    }

    // epilogue: frag F -> proj/col; V transposed
    #pragma unroll
    for (int f = 0; f < 6; ++f) {
        const int F = wv * 6 + f;      // wv is runtime but F>>3 etc. stay cheap
        const int p = F >> 3;
        const int col = (F & 7) * 16 + lo;
        const float* bias = (p == 0) ? bq : (p == 1) ? bk : bv;
        float bvv = bias[col];
        if (p == 2) {
            const int mb = m0 >> 12, s0l = m0 & 4095;
            #pragma unroll
            for (int rg = 0; rg < 2; ++rg)
                #pragma unroll
                for (int i = 0; i < 4; ++i) {
                    int s = s0l + rg * 16 + hi * 4 + i;
                    Vtg[((size_t)mb * Hh + col) * Ss + s] = (bf16)(acc[rg][f][i] + bvv);
                }
        } else {
            bf16* dst = (p == 0) ? Qb : Kb;
            const float scale = (p == 0) ? 0.08838834764831843f : 1.0f;
            #pragma unroll
            for (int rg = 0; rg < 2; ++rg)
                #pragma unroll
                for (int i = 0; i < 4; ++i) {
                    int row = m0 + rg * 16 + hi * 4 + i;
                    dst[(size_t)row * Hh + col] = (bf16)((acc[rg][f][i] + bvv) * scale);
                }
        }
    }
}

// ---------------------------------------------------------------------------
// Kernel 2: split-KV causal flash attention, swapped QK^T, QBLK=128.
// grid (S/128, B, NC), block 256 (4 waves x 32 q-rows, 2 q-groups each).
// Chunk c handles kv tiles {c, c+NC, ...} <= 2qb+1 (balanced strided).
// ---------------------------------------------------------------------------
__global__ __launch_bounds__(256, 2) void attn_kernel(
    const bf16* __restrict__ Qb, const bf16* __restrict__ Kb,
    const bf16* __restrict__ Vtg,
    float* __restrict__ Opart, float* __restrict__ Mpart, float* __restrict__ Lpart,
    int NC)
{
    __shared__ bf16 Ks[64][136];   // K tile, stride 272B
    __shared__ bf16 Vt[128][64];   // V^T tile, (h&7)-XOR swizzled 16B chunks
    __shared__ bf16 Ps[4][32][72]; // wave-private P[q][kv], 2 q-groups

    const int t = threadIdx.x;
    const int wv = t >> 6, lane = t & 63, lo = lane & 15, hi = lane >> 4;
    const int qb = blockIdx.x, b = blockIdx.y, c = blockIdx.z;
    const int tlast = 2 * qb + 1;
    if (c > tlast) return;
    const int q0 = qb * QB;
    const size_t base = (size_t)b * Ss * Hh;
    const size_t vbase = (size_t)b * Hh * Ss;

    // staging pointers (rep offsets compile-time)
    const bf16* kg = Kb + base + (size_t)(t >> 4) * Hh + (t & 15) * 8;
    const bf16* vg = Vtg + vbase + (size_t)(t >> 3) * Ss + (t & 7) * 8;
    bf16* ksl = &Ks[t >> 4][(t & 15) * 8];
    bf16* vsl = &Vt[t >> 3][((t & 7) * 8) ^ (((t >> 3) & 7) << 3)];

    // Q fragments: 2 q-groups x 4 k-steps
    bf16x8 qf[2][4];
    #pragma unroll
    for (int g = 0; g < 2; ++g)
        #pragma unroll
        for (int kk = 0; kk < 4; ++kk)
            qf[g][kk] = *(const bf16x8*)(
                Qb + base + (size_t)(q0 + wv * 32 + g * 16 + lo) * Hh + kk * 32 + hi * 8);

    f32x4 acc[2][8];
    #pragma unroll
    for (int g = 0; g < 2; ++g)
        #pragma unroll
        for (int f = 0; f < 8; ++f) acc[g][f] = f32x4{0.f, 0.f, 0.f, 0.f};
    float M_[2] = {-INFINITY, -INFINITY};
    float L_[2] = {0.f, 0.f};

    uint4 kr0, kr1, kr2, kr3, vr0, vr1, vr2, vr3;
#define ISSUE(T) do {                                            \
        const bf16* kp_ = kg + (size_t)(T) * (64 * Hh);          \
        kr0 = *(const uint4*)(kp_);                              \
        kr1 = *(const uint4*)(kp_ + 16 * Hh);                    \
        kr2 = *(const uint4*)(kp_ + 32 * Hh);                    \
        kr3 = *(const uint4*)(kp_ + 48 * Hh);                    \
        const bf16* vp_ = vg + (T) * 64;                         \
        vr0 = *(const uint4*)(vp_);                              \
        vr1 = *(const uint4*)(vp_ + 32 * Ss);                    \
        vr2 = *(const uint4*)(vp_ + 64 * Ss);                    \
        vr3 = *(const uint4*)(vp_ + 96 * Ss);                    \
    } while (0)

    ISSUE(c);
    for (int tile = c; tile <= tlast; tile += NC) {
        __syncthreads();   // previous tile's LDS reads done
        *(uint4*)(ksl) = kr0;
        *(uint4*)(ksl + 16 * 136) = kr1;
        *(uint4*)(ksl + 32 * 136) = kr2;
        *(uint4*)(ksl + 48 * 136) = kr3;
        *(uint4*)(vsl) = vr0;
        *(uint4*)(vsl + 32 * 64) = vr1;
        *(uint4*)(vsl + 64 * 64) = vr2;
        *(uint4*)(vsl + 96 * 64) = vr3;
        const int tn = tile + NC;
        if (tn <= tlast) ISSUE(tn);
        __syncthreads();
        const int kv0 = tile * 64;

        // S^T = K Q^T per q-group: D[kv][q], kv = f*16+hi*4+i, q = lo
        f32x4 sv[2][4];
        #pragma unroll
        for (int g = 0; g < 2; ++g)
            #pragma unroll
            for (int f = 0; f < 4; ++f) sv[g][f] = f32x4{0.f, 0.f, 0.f, 0.f};
        __builtin_amdgcn_s_setprio(1);
        #pragma unroll
        for (int kk = 0; kk < 4; ++kk) {
            #pragma unroll
            for (int f = 0; f < 4; ++f) {
                bf16x8 kf = *(const bf16x8*)&Ks[f * 16 + lo][kk * 32 + hi * 8];
                sv[0][f] = MFMA16(kf, qf[0][kk], sv[0][f]);
                sv[1][f] = MFMA16(kf, qf[1][kk], sv[1][f]);
            }
        }
        __builtin_amdgcn_s_setprio(0);

        #pragma unroll
        for (int g = 0; g < 2; ++g) {
            const int qg0 = q0 + wv * 32 + g * 16;   // wave-uniform per g
            if (kv0 + 63 > qg0) {                    // masking needed
                int qg = qg0 + lo;
                #pragma unroll
                for (int f = 0; f < 4; ++f)
                    #pragma unroll
                    for (int i = 0; i < 4; ++i)
                        if (kv0 + f * 16 + hi * 4 + i > qg) sv[g][f][i] = -INFINITY;
            }
            // online softmax: lane owns 16 kv of row q=lo; tree + 2 shuffles
            float pm = -INFINITY;
            #pragma unroll
            for (int f = 0; f < 4; ++f)
                pm = fmaxf(pm, fmaxf(fmaxf(sv[g][f][0], sv[g][f][1]),
                                     fmaxf(sv[g][f][2], sv[g][f][3])));
            pm = fmaxf(pm, __shfl_xor(pm, 16));
            pm = fmaxf(pm, __shfl_xor(pm, 32));
            float nM = fmaxf(M_[g], pm);
            float nMs = fmaxf(nM, -1e37f);           // guard fully-masked group
            float scn = __expf(M_[g] - nMs);
            float rs = 0.f;
            #pragma unroll
            for (int f = 0; f < 4; ++f)
                #pragma unroll
                for (int i = 0; i < 4; ++i) {
                    float e = __expf(sv[g][f][i] - nMs);
                    sv[g][f][i] = e;
                    rs += e;
                }
            rs += __shfl_xor(rs, 16);
            rs += __shfl_xor(rs, 32);
            L_[g] = L_[g] * scn + rs;
            M_[g] = nM;
            // rescale O: acc row q' = hi*4+i needs scn of lane lo=q' (same hi)
            #pragma unroll
            for (int i = 0; i < 4; ++i) {
                float si = __shfl(scn, (lane & 48) + hi * 4 + i);
                #pragma unroll
                for (int f = 0; f < 8; ++f) acc[g][f][i] *= si;
            }
            // P -> wave-private LDS as P[q][kv]
            #pragma unroll
            for (int f = 0; f < 4; ++f)
                #pragma unroll
                for (int i = 0; i < 4; ++i)
                    Ps[wv][g * 16 + lo][f * 16 + hi * 4 + i] = (bf16)sv[g][f][i];
        }
        // O += P V
        __builtin_amdgcn_s_setprio(1);
        #pragma unroll
        for (int kk = 0; kk < 2; ++kk) {
            bf16x8 pa0 = *(const bf16x8*)&Ps[wv][lo][kk * 32 + hi * 8];
            bf16x8 pa1 = *(const bf16x8*)&Ps[wv][16 + lo][kk * 32 + hi * 8];
            #pragma unroll
            for (int f = 0; f < 8; ++f) {
                int row = f * 16 + lo;
                bf16x8 vf = *(const bf16x8*)&Vt[row][(kk * 32 + hi * 8) ^ ((row & 7) << 3)];
                acc[0][f] = MFMA16(pa0, vf, acc[0][f]);
                acc[1][f] = MFMA16(pa1, vf, acc[1][f]);
            }
        }
        __builtin_amdgcn_s_setprio(0);
    }
#undef ISSUE
    // write unnormalized partials
    const size_t pb = (((size_t)b * NQB + qb) * NC + c) * QB;
    #pragma unroll
    for (int g = 0; g < 2; ++g)
        #pragma unroll
        for (int f = 0; f < 8; ++f)
            #pragma unroll
            for (int i = 0; i < 4; ++i) {
                int row = wv * 32 + g * 16 + hi * 4 + i;
                Opart[(pb + row) * 128 + f * 16 + lo] = acc[g][f][i];
            }
    if (hi == 0) {
        #pragma unroll
        for (int g = 0; g < 2; ++g) {
            Mpart[pb + wv * 32 + g * 16 + lo] = M_[g];
            Lpart[pb + wv * 32 + g * 16 + lo] = L_[g];
        }
    }
}

// ---------------------------------------------------------------------------
// Kernel 3: combine chunk partials. grid (S/128, B), block 256.
// ---------------------------------------------------------------------------
__global__ __launch_bounds__(256) void reduce_kernel(
    const float* __restrict__ Opart, const float* __restrict__ Mpart,
    const float* __restrict__ Lpart, float* __restrict__ out, int NC)
{
    __shared__ float wexp[4][128];
    __shared__ float invL[128];
    const int qb = blockIdx.x, b = blockIdx.y, t = threadIdx.x;
    const int nact = min(NC, 2 * qb + 2);
    const size_t pb = ((size_t)b * NQB + qb) * NC * QB;
    if (t < 128) {
        float Mstar = -INFINITY;
        for (int c = 0; c < nact; ++c) Mstar = fmaxf(Mstar, Mpart[pb + c * QB + t]);
        float Ls = 0.f;
        for (int c = 0; c < nact; ++c) {
            float wc = __expf(Mpart[pb + c * QB + t] - Mstar);
            wexp[c][t] = wc;
            Ls += wc * Lpart[pb + c * QB + t];
        }
        invL[t] = 1.f / Ls;
    }
    __syncthreads();
    #pragma unroll
    for (int rep = 0; rep < 16; ++rep) {
        int idx = rep * 256 + t;
        int row = idx >> 5, c4 = (idx & 31) * 4;
        float ox = 0.f, oy = 0.f, oz = 0.f, ow = 0.f;
        for (int c = 0; c < nact; ++c) {
            float wc = wexp[c][row];
            float4 v = *(const float4*)(Opart + (pb + (size_t)c * QB + row) * 128 + c4);
            ox += wc * v.x; oy += wc * v.y; oz += wc * v.z; ow += wc * v.w;
        }
        float il = invL[row];
        float4 o = make_float4(ox * il, oy * il, oz * il, ow * il);
        *(float4*)(out + ((size_t)b * Ss + qb * QB + row) * 128 + c4) = o;
    }
}

extern "C" void kernel_launch(void* const* d_in, const int* in_sizes, int n_in,
                              void* d_out, int out_size, void* d_ws, size_t ws_size,
                              hipStream_t stream) {
    (void)in_sizes; (void)n_in; (void)out_size;
    const float* embds = (const float*)d_in[0];
    const float* Wq = (const float*)d_in[1];
    const float* bq = (const float*)d_in[2];
    const float* Wk = (const float*)d_in[3];
    const float* bk = (const float*)d_in[4];
    const float* Wv = (const float*)d_in[5];
    const float* bv = (const float*)d_in[6];

    char* ws = (char*)d_ws;
    size_t off = 0;
    bf16* Qb  = (bf16*)(ws + off); off += (size_t)Mrows * Hh * 2;
    bf16* Kb  = (bf16*)(ws + off); off += (size_t)Mrows * Hh * 2;
    bf16* Vtg = (bf16*)(ws + off); off += (size_t)Mrows * Hh * 2;
    bf16* Wt  = (bf16*)(ws + off); off += (size_t)3 * Hh * Ee * 2;

    int NC = 4;
    {
        auto need = [&](int nc) -> size_t {
            return off + (size_t)Bb * NQB * nc * QB * 128 * 4
                       + (size_t)Bb * NQB * nc * QB * 4 * 2;
        };
        if (need(NC) > ws_size) NC = 2;
        if (need(NC) > ws_size) NC = 1;
    }
    float* Opart = (float*)(ws + off);
    size_t osz = (size_t)Bb * NQB * NC * QB * 128 * 4;
    float* Mp = (float*)(ws + off + osz);
    float* Lp = Mp + (size_t)Bb * NQB * NC * QB;

    wprep_kernel<<<dim3(Ee / 16, 3), 256, 0, stream>>>(Wq, Wk, Wv, Wt);
    proj_kernel<<<dim3(Mrows / 32), 256, 0, stream>>>(embds, Wt, bq, bk, bv, Qb, Kb, Vtg);
    attn_kernel<<<dim3(NQB, Bb, NC), 256, 0, stream>>>(Qb, Kb, Vtg, Opart, Mp, Lp, NC);
    reduce_kernel<<<dim3(NQB, Bb), 256, 0, stream>>>(Opart, Mp, Lp, (float*)d_out, NC);
}

// Round 6
// 121.878 us; speedup vs baseline: 1.1339x; 1.1339x over previous
//
#include <hip/hip_runtime.h>

typedef __bf16 bf16;
typedef __attribute__((ext_vector_type(4))) bf16 bf16x4;
typedef __attribute__((ext_vector_type(8))) bf16 bf16x8;
typedef __attribute__((ext_vector_type(4))) float f32x4;

#define MFMA16(a, b, c) __builtin_amdgcn_mfma_f32_16x16x32_bf16(a, b, c, 0, 0, 0)

constexpr int Bb = 4, Ss = 4096, Ee = 1024, Hh = 128;
constexpr int Mrows = Bb * Ss;  // 16384
constexpr int QB = 128;         // attn q-block
constexpr int NQB = Ss / QB;    // 32

// ---------------------------------------------------------------------------
// Kernel 0: W prep. Transpose W [E,H] f32 -> Wt [3][H][E] bf16.
// grid (E/16, 3), block 256.
// ---------------------------------------------------------------------------
__global__ __launch_bounds__(256) void wprep_kernel(
    const float* __restrict__ Wq, const float* __restrict__ Wk,
    const float* __restrict__ Wv, bf16* __restrict__ Wt)
{
    __shared__ bf16 Sb[16][136];
    const int w = blockIdx.y;
    const float* W = (w == 0) ? Wq : (w == 1) ? Wk : Wv;
    const int k0 = blockIdx.x * 16;
    const int t = threadIdx.x;
    {
        int r = t >> 4, cg = (t & 15) * 8;
        const float4* src = (const float4*)(W + (size_t)(k0 + r) * Hh + cg);
        float4 v0 = src[0], v1 = src[1];
        bf16x4 o0, o1;
        o0[0] = (bf16)v0.x; o0[1] = (bf16)v0.y; o0[2] = (bf16)v0.z; o0[3] = (bf16)v0.w;
        o1[0] = (bf16)v1.x; o1[1] = (bf16)v1.y; o1[2] = (bf16)v1.z; o1[3] = (bf16)v1.w;
        *(bf16x4*)&Sb[r][cg] = o0;
        *(bf16x4*)&Sb[r][cg + 4] = o1;
    }
    __syncthreads();
    {
        int h = t >> 1, kseg = (t & 1) * 8;
        bf16x8 v;
        #pragma unroll
        for (int e = 0; e < 8; ++e) v[e] = Sb[kseg + e][h];
        *(bf16x8*)&Wt[((size_t)w * Hh + h) * Ee + k0 + kseg] = v;
    }
}

// ---------------------------------------------------------------------------
// Kernel 1: fused QKV projection, register-prefetch pipelined.
// grid (Mrows/64) = 256, block 256 (4 waves). Per k-tile (64 k): A staged
// 64x64 f32->bf16, B staged 3x128x64 bf16 (uint4 copies); NEXT tile's
// loads issued into named registers while MFMA runs on current tile.
// V written transposed: Vtg[b][h][s]. Q pre-scaled by 1/sqrt(H).
// ---------------------------------------------------------------------------
__global__ __launch_bounds__(256, 2) void proj_kernel(
    const float* __restrict__ embds, const bf16* __restrict__ Wt,
    const float* __restrict__ bq, const float* __restrict__ bk,
    const float* __restrict__ bv,
    bf16* __restrict__ Qb, bf16* __restrict__ Kb, bf16* __restrict__ Vtg)
{
    __shared__ bf16 As[64][72];
    __shared__ bf16 Bs[3][128][72];

    const int t = threadIdx.x;
    const int wv = t >> 6, lane = t & 63, lo = lane & 15, hi = lane >> 4;
    const int m0 = blockIdx.x * 64;

    f32x4 acc[3][8];
    #pragma unroll
    for (int w = 0; w < 3; ++w)
        #pragma unroll
        for (int f = 0; f < 8; ++f) acc[w][f] = f32x4{0.f, 0.f, 0.f, 0.f};

    // A staging: thread owns row (t>>2), 16 contiguous cols at (t&3)*16
    const int arow = t >> 2, acg = (t & 3) * 16;
    const float4* ag = (const float4*)(embds + (size_t)(m0 + arow) * Ee + acg);
    bf16* asl = &As[arow][acg];
    // B staging: thread base; rep r covers (w = r>>2, row = (r&3)*32 + (t>>3), c = t&7)
    const bf16* bg = Wt + (size_t)(t >> 3) * Ee + (t & 7) * 8;
    bf16* bsl = &Bs[0][t >> 3][(t & 7) * 8];

    float4 ar0, ar1, ar2, ar3;
    uint4 br0, br1, br2, br3, br4, br5, br6, br7, br8, br9, br10, br11;

#define BGOFF(r) ((size_t)((r) >> 2) * (Hh * Ee) + (size_t)((r) & 3) * (32 * Ee))
#define BLOFF(r) (((r) >> 2) * (128 * 72) + ((r) & 3) * (32 * 72))
#define ISSUE(K0) do {                                           \
        const float4* ap_ = ag + (K0) / 4;                       \
        ar0 = ap_[0]; ar1 = ap_[1]; ar2 = ap_[2]; ar3 = ap_[3];  \
        const bf16* bp_ = bg + (K0);                             \
        br0  = *(const uint4*)(bp_ + BGOFF(0));                  \
        br1  = *(const uint4*)(bp_ + BGOFF(1));                  \
        br2  = *(const uint4*)(bp_ + BGOFF(2));                  \
        br3  = *(const uint4*)(bp_ + BGOFF(3));                  \
        br4  = *(const uint4*)(bp_ + BGOFF(4));                  \
        br5  = *(const uint4*)(bp_ + BGOFF(5));                  \
        br6  = *(const uint4*)(bp_ + BGOFF(6));                  \
        br7  = *(const uint4*)(bp_ + BGOFF(7));                  \
        br8  = *(const uint4*)(bp_ + BGOFF(8));                  \
        br9  = *(const uint4*)(bp_ + BGOFF(9));                  \
        br10 = *(const uint4*)(bp_ + BGOFF(10));                 \
        br11 = *(const uint4*)(bp_ + BGOFF(11));                 \
    } while (0)
#define CVT4(dst, v) do { bf16x4 o_;                             \
        o_[0] = (bf16)(v).x; o_[1] = (bf16)(v).y;                \
        o_[2] = (bf16)(v).z; o_[3] = (bf16)(v).w;                \
        *(bf16x4*)(dst) = o_; } while (0)

    ISSUE(0);
    for (int k0 = 0; k0 < Ee; k0 += 64) {
        __syncthreads();   // previous tile's LDS reads done
        CVT4(asl + 0, ar0); CVT4(asl + 4, ar1);
        CVT4(asl + 8, ar2); CVT4(asl + 12, ar3);
        *(uint4*)(bsl + BLOFF(0))  = br0;
        *(uint4*)(bsl + BLOFF(1))  = br1;
        *(uint4*)(bsl + BLOFF(2))  = br2;
        *(uint4*)(bsl + BLOFF(3))  = br3;
        *(uint4*)(bsl + BLOFF(4))  = br4;
        *(uint4*)(bsl + BLOFF(5))  = br5;
        *(uint4*)(bsl + BLOFF(6))  = br6;
        *(uint4*)(bsl + BLOFF(7))  = br7;
        *(uint4*)(bsl + BLOFF(8))  = br8;
        *(uint4*)(bsl + BLOFF(9))  = br9;
        *(uint4*)(bsl + BLOFF(10)) = br10;
        *(uint4*)(bsl + BLOFF(11)) = br11;
        if (k0 + 64 < Ee) ISSUE(k0 + 64);
        __syncthreads();
        __builtin_amdgcn_s_setprio(1);
        #pragma unroll
        for (int kk = 0; kk < 2; ++kk) {
            bf16x8 a = *(const bf16x8*)&As[wv * 16 + lo][kk * 32 + hi * 8];
            #pragma unroll
            for (int w = 0; w < 3; ++w)
                #pragma unroll
                for (int f = 0; f < 8; ++f) {
                    bf16x8 b = *(const bf16x8*)&Bs[w][f * 16 + lo][kk * 32 + hi * 8];
                    acc[w][f] = MFMA16(a, b, acc[w][f]);
                }
        }
        __builtin_amdgcn_s_setprio(0);
    }
#undef ISSUE
#undef BGOFF
#undef BLOFF
#undef CVT4
    // epilogue
    {   // Q (scaled)
        #pragma unroll
        for (int f = 0; f < 8; ++f) {
            int col = f * 16 + lo;
            float bvv = bq[col];
            #pragma unroll
            for (int i = 0; i < 4; ++i) {
                int row = m0 + wv * 16 + hi * 4 + i;
                Qb[(size_t)row * Hh + col] =
                    (bf16)((acc[0][f][i] + bvv) * 0.08838834764831843f);
            }
        }
    }
    {   // K
        #pragma unroll
        for (int f = 0; f < 8; ++f) {
            int col = f * 16 + lo;
            float bvv = bk[col];
            #pragma unroll
            for (int i = 0; i < 4; ++i) {
                int row = m0 + wv * 16 + hi * 4 + i;
                Kb[(size_t)row * Hh + col] = (bf16)(acc[1][f][i] + bvv);
            }
        }
    }
    {   // V transposed: Vtg[b][h][s]
        const int mb = m0 >> 12, s0l = m0 & 4095;
        #pragma unroll
        for (int f = 0; f < 8; ++f) {
            int h = f * 16 + lo;
            float bvv = bv[h];
            #pragma unroll
            for (int i = 0; i < 4; ++i) {
                int s = s0l + wv * 16 + hi * 4 + i;
                Vtg[((size_t)mb * Hh + h) * Ss + s] = (bf16)(acc[2][f][i] + bvv);
            }
        }
    }
}

// ---------------------------------------------------------------------------
// Kernel 2: split-KV causal flash attention, swapped QK^T, QBLK=128.
// grid (S/128, B, NC), block 256 (4 waves x 32 q-rows, 2 q-groups each).
// Chunk c handles kv tiles {c, c+NC, ...} <= 2qb+1 (balanced strided).
// ---------------------------------------------------------------------------
__global__ __launch_bounds__(256, 2) void attn_kernel(
    const bf16* __restrict__ Qb, const bf16* __restrict__ Kb,
    const bf16* __restrict__ Vtg,
    float* __restrict__ Opart, float* __restrict__ Mpart, float* __restrict__ Lpart,
    int NC)
{
    __shared__ bf16 Ks[64][136];   // K tile, stride 272B
    __shared__ bf16 Vt[128][64];   // V^T tile, (h&7)-XOR swizzled 16B chunks
    __shared__ bf16 Ps[4][32][72]; // wave-private P[q][kv], 2 q-groups

    const int t = threadIdx.x;
    const int wv = t >> 6, lane = t & 63, lo = lane & 15, hi = lane >> 4;
    const int qb = blockIdx.x, b = blockIdx.y, c = blockIdx.z;
    const int tlast = 2 * qb + 1;
    if (c > tlast) return;
    const int q0 = qb * QB;
    const size_t base = (size_t)b * Ss * Hh;
    const size_t vbase = (size_t)b * Hh * Ss;

    // staging pointers (rep offsets compile-time)
    const bf16* kg = Kb + base + (size_t)(t >> 4) * Hh + (t & 15) * 8;
    const bf16* vg = Vtg + vbase + (size_t)(t >> 3) * Ss + (t & 7) * 8;
    bf16* ksl = &Ks[t >> 4][(t & 15) * 8];
    bf16* vsl = &Vt[t >> 3][((t & 7) * 8) ^ (((t >> 3) & 7) << 3)];

    // Q fragments: 2 q-groups x 4 k-steps
    bf16x8 qf[2][4];
    #pragma unroll
    for (int g = 0; g < 2; ++g)
        #pragma unroll
        for (int kk = 0; kk < 4; ++kk)
            qf[g][kk] = *(const bf16x8*)(
                Qb + base + (size_t)(q0 + wv * 32 + g * 16 + lo) * Hh + kk * 32 + hi * 8);

    f32x4 acc[2][8];
    #pragma unroll
    for (int g = 0; g < 2; ++g)
        #pragma unroll
        for (int f = 0; f < 8; ++f) acc[g][f] = f32x4{0.f, 0.f, 0.f, 0.f};
    float M_[2] = {-INFINITY, -INFINITY};
    float L_[2] = {0.f, 0.f};

    uint4 kr0, kr1, kr2, kr3, vr0, vr1, vr2, vr3;
#define ISSUE(T) do {                                            \
        const bf16* kp_ = kg + (size_t)(T) * (64 * Hh);          \
        kr0 = *(const uint4*)(kp_);                              \
        kr1 = *(const uint4*)(kp_ + 16 * Hh);                    \
        kr2 = *(const uint4*)(kp_ + 32 * Hh);                    \
        kr3 = *(const uint4*)(kp_ + 48 * Hh);                    \
        const bf16* vp_ = vg + (T) * 64;                         \
        vr0 = *(const uint4*)(vp_);                              \
        vr1 = *(const uint4*)(vp_ + 32 * Ss);                    \
        vr2 = *(const uint4*)(vp_ + 64 * Ss);                    \
        vr3 = *(const uint4*)(vp_ + 96 * Ss);                    \
    } while (0)

    ISSUE(c);
    for (int tile = c; tile <= tlast; tile += NC) {
        __syncthreads();   // previous tile's LDS reads done
        *(uint4*)(ksl) = kr0;
        *(uint4*)(ksl + 16 * 136) = kr1;
        *(uint4*)(ksl + 32 * 136) = kr2;
        *(uint4*)(ksl + 48 * 136) = kr3;
        *(uint4*)(vsl) = vr0;
        *(uint4*)(vsl + 32 * 64) = vr1;
        *(uint4*)(vsl + 64 * 64) = vr2;
        *(uint4*)(vsl + 96 * 64) = vr3;
        const int tn = tile + NC;
        if (tn <= tlast) ISSUE(tn);
        __syncthreads();
        const int kv0 = tile * 64;

        // S^T = K Q^T per q-group: D[kv][q], kv = f*16+hi*4+i, q = lo
        f32x4 sv[2][4];
        #pragma unroll
        for (int g = 0; g < 2; ++g)
            #pragma unroll
            for (int f = 0; f < 4; ++f) sv[g][f] = f32x4{0.f, 0.f, 0.f, 0.f};
        __builtin_amdgcn_s_setprio(1);
        #pragma unroll
        for (int kk = 0; kk < 4; ++kk) {
            #pragma unroll
            for (int f = 0; f < 4; ++f) {
                bf16x8 kf = *(const bf16x8*)&Ks[f * 16 + lo][kk * 32 + hi * 8];
                sv[0][f] = MFMA16(kf, qf[0][kk], sv[0][f]);
                sv[1][f] = MFMA16(kf, qf[1][kk], sv[1][f]);
            }
        }
        __builtin_amdgcn_s_setprio(0);

        #pragma unroll
        for (int g = 0; g < 2; ++g) {
            const int qg0 = q0 + wv * 32 + g * 16;   // wave-uniform per g
            if (kv0 + 63 > qg0) {                    // masking needed
                int qg = qg0 + lo;
                #pragma unroll
                for (int f = 0; f < 4; ++f)
                    #pragma unroll
                    for (int i = 0; i < 4; ++i)
                        if (kv0 + f * 16 + hi * 4 + i > qg) sv[g][f][i] = -INFINITY;
            }
            // online softmax: lane owns 16 kv of row q=lo; tree + 2 shuffles
            float pm = -INFINITY;
            #pragma unroll
            for (int f = 0; f < 4; ++f)
                pm = fmaxf(pm, fmaxf(fmaxf(sv[g][f][0], sv[g][f][1]),
                                     fmaxf(sv[g][f][2], sv[g][f][3])));
            pm = fmaxf(pm, __shfl_xor(pm, 16));
            pm = fmaxf(pm, __shfl_xor(pm, 32));
            float nM = fmaxf(M_[g], pm);
            float nMs = fmaxf(nM, -1e37f);           // guard fully-masked group
            float scn = __expf(M_[g] - nMs);
            float rs = 0.f;
            #pragma unroll
            for (int f = 0; f < 4; ++f)
                #pragma unroll
                for (int i = 0; i < 4; ++i) {
                    float e = __expf(sv[g][f][i] - nMs);
                    sv[g][f][i] = e;
                    rs += e;
                }
            rs += __shfl_xor(rs, 16);
            rs += __shfl_xor(rs, 32);
            L_[g] = L_[g] * scn + rs;
            M_[g] = nM;
            // rescale O: acc row q' = hi*4+i needs scn of lane lo=q' (same hi)
            #pragma unroll
            for (int i = 0; i < 4; ++i) {
                float si = __shfl(scn, (lane & 48) + hi * 4 + i);
                #pragma unroll
                for (int f = 0; f < 8; ++f) acc[g][f][i] *= si;
            }
            // P -> wave-private LDS as P[q][kv]
            #pragma unroll
            for (int f = 0; f < 4; ++f)
                #pragma unroll
                for (int i = 0; i < 4; ++i)
                    Ps[wv][g * 16 + lo][f * 16 + hi * 4 + i] = (bf16)sv[g][f][i];
        }
        // O += P V
        __builtin_amdgcn_s_setprio(1);
        #pragma unroll
        for (int kk = 0; kk < 2; ++kk) {
            bf16x8 pa0 = *(const bf16x8*)&Ps[wv][lo][kk * 32 + hi * 8];
            bf16x8 pa1 = *(const bf16x8*)&Ps[wv][16 + lo][kk * 32 + hi * 8];
            #pragma unroll
            for (int f = 0; f < 8; ++f) {
                int row = f * 16 + lo;
                bf16x8 vf = *(const bf16x8*)&Vt[row][(kk * 32 + hi * 8) ^ ((row & 7) << 3)];
                acc[0][f] = MFMA16(pa0, vf, acc[0][f]);
                acc[1][f] = MFMA16(pa1, vf, acc[1][f]);
            }
        }
        __builtin_amdgcn_s_setprio(0);
    }
#undef ISSUE
    // write unnormalized partials
    const size_t pb = (((size_t)b * NQB + qb) * NC + c) * QB;
    #pragma unroll
    for (int g = 0; g < 2; ++g)
        #pragma unroll
        for (int f = 0; f < 8; ++f)
            #pragma unroll
            for (int i = 0; i < 4; ++i) {
                int row = wv * 32 + g * 16 + hi * 4 + i;
                Opart[(pb + row) * 128 + f * 16 + lo] = acc[g][f][i];
            }
    if (hi == 0) {
        #pragma unroll
        for (int g = 0; g < 2; ++g) {
            Mpart[pb + wv * 32 + g * 16 + lo] = M_[g];
            Lpart[pb + wv * 32 + g * 16 + lo] = L_[g];
        }
    }
}

// ---------------------------------------------------------------------------
// Kernel 3: combine chunk partials. grid (S/128, B), block 256.
// ---------------------------------------------------------------------------
__global__ __launch_bounds__(256) void reduce_kernel(
    const float* __restrict__ Opart, const float* __restrict__ Mpart,
    const float* __restrict__ Lpart, float* __restrict__ out, int NC)
{
    __shared__ float wexp[4][128];
    __shared__ float invL[128];
    const int qb = blockIdx.x, b = blockIdx.y, t = threadIdx.x;
    const int nact = min(NC, 2 * qb + 2);
    const size_t pb = ((size_t)b * NQB + qb) * NC * QB;
    if (t < 128) {
        float Mstar = -INFINITY;
        for (int c = 0; c < nact; ++c) Mstar = fmaxf(Mstar, Mpart[pb + c * QB + t]);
        float Ls = 0.f;
        for (int c = 0; c < nact; ++c) {
            float wc = __expf(Mpart[pb + c * QB + t] - Mstar);
            wexp[c][t] = wc;
            Ls += wc * Lpart[pb + c * QB + t];
        }
        invL[t] = 1.f / Ls;
    }
    __syncthreads();
    #pragma unroll
    for (int rep = 0; rep < 16; ++rep) {
        int idx = rep * 256 + t;
        int row = idx >> 5, c4 = (idx & 31) * 4;
        float ox = 0.f, oy = 0.f, oz = 0.f, ow = 0.f;
        for (int c = 0; c < nact; ++c) {
            float wc = wexp[c][row];
            float4 v = *(const float4*)(Opart + (pb + (size_t)c * QB + row) * 128 + c4);
            ox += wc * v.x; oy += wc * v.y; oz += wc * v.z; ow += wc * v.w;
        }
        float il = invL[row];
        float4 o = make_float4(ox * il, oy * il, oz * il, ow * il);
        *(float4*)(out + ((size_t)b * Ss + qb * QB + row) * 128 + c4) = o;
    }
}

extern "C" void kernel_launch(void* const* d_in, const int* in_sizes, int n_in,
                              void* d_out, int out_size, void* d_ws, size_t ws_size,
                              hipStream_t stream) {
    (void)in_sizes; (void)n_in; (void)out_size;
    const float* embds = (const float*)d_in[0];
    const float* Wq = (const float*)d_in[1];
    const float* bq = (const float*)d_in[2];
    const float* Wk = (const float*)d_in[3];
    const float* bk = (const float*)d_in[4];
    const float* Wv = (const float*)d_in[5];
    const float* bv = (const float*)d_in[6];

    char* ws = (char*)d_ws;
    size_t off = 0;
    bf16* Qb  = (bf16*)(ws + off); off += (size_t)Mrows * Hh * 2;
    bf16* Kb  = (bf16*)(ws + off); off += (size_t)Mrows * Hh * 2;
    bf16* Vtg = (bf16*)(ws + off); off += (size_t)Mrows * Hh * 2;
    bf16* Wt  = (bf16*)(ws + off); off += (size_t)3 * Hh * Ee * 2;

    int NC = 4;
    {
        auto need = [&](int nc) -> size_t {
            return off + (size_t)Bb * NQB * nc * QB * 128 * 4
                       + (size_t)Bb * NQB * nc * QB * 4 * 2;
        };
        if (need(NC) > ws_size) NC = 2;
        if (need(NC) > ws_size) NC = 1;
    }
    float* Opart = (float*)(ws + off);
    size_t osz = (size_t)Bb * NQB * NC * QB * 128 * 4;
    float* Mp = (float*)(ws + off + osz);
    float* Lp = Mp + (size_t)Bb * NQB * NC * QB;

    wprep_kernel<<<dim3(Ee / 16, 3), 256, 0, stream>>>(Wq, Wk, Wv, Wt);
    proj_kernel<<<dim3(Mrows / 64), 256, 0, stream>>>(embds, Wt, bq, bk, bv, Qb, Kb, Vtg);
    attn_kernel<<<dim3(NQB, Bb, NC), 256, 0, stream>>>(Qb, Kb, Vtg, Opart, Mp, Lp, NC);
    reduce_kernel<<<dim3(NQB, Bb), 256, 0, stream>>>(Opart, Mp, Lp, (float*)d_out, NC);
}

// Round 7
// 110.068 us; speedup vs baseline: 1.2556x; 1.1073x over previous
//
#include <hip/hip_runtime.h>

typedef __bf16 bf16;
typedef __attribute__((ext_vector_type(4))) bf16 bf16x4;
typedef __attribute__((ext_vector_type(8))) bf16 bf16x8;
typedef __attribute__((ext_vector_type(4))) float f32x4;

#define MFMA16(a, b, c) __builtin_amdgcn_mfma_f32_16x16x32_bf16(a, b, c, 0, 0, 0)

constexpr int Bb = 4, Ss = 4096, Ee = 1024, Hh = 128;
constexpr int Mrows = Bb * Ss;  // 16384
constexpr int QB = 128;         // attn q-block
constexpr int NQB = Ss / QB;    // 32

// ---------------------------------------------------------------------------
// Kernel 0: W prep. Transpose W [E,H] f32 -> Wt [3][H][E] bf16.
// grid (E/16, 3), block 256.
// ---------------------------------------------------------------------------
__global__ __launch_bounds__(256) void wprep_kernel(
    const float* __restrict__ Wq, const float* __restrict__ Wk,
    const float* __restrict__ Wv, bf16* __restrict__ Wt)
{
    __shared__ bf16 Sb[16][136];
    const int w = blockIdx.y;
    const float* W = (w == 0) ? Wq : (w == 1) ? Wk : Wv;
    const int k0 = blockIdx.x * 16;
    const int t = threadIdx.x;
    {
        int r = t >> 4, cg = (t & 15) * 8;
        const float4* src = (const float4*)(W + (size_t)(k0 + r) * Hh + cg);
        float4 v0 = src[0], v1 = src[1];
        bf16x4 o0, o1;
        o0[0] = (bf16)v0.x; o0[1] = (bf16)v0.y; o0[2] = (bf16)v0.z; o0[3] = (bf16)v0.w;
        o1[0] = (bf16)v1.x; o1[1] = (bf16)v1.y; o1[2] = (bf16)v1.z; o1[3] = (bf16)v1.w;
        *(bf16x4*)&Sb[r][cg] = o0;
        *(bf16x4*)&Sb[r][cg + 4] = o1;
    }
    __syncthreads();
    {
        int h = t >> 1, kseg = (t & 1) * 8;
        bf16x8 v;
        #pragma unroll
        for (int e = 0; e < 8; ++e) v[e] = Sb[kseg + e][h];
        *(bf16x8*)&Wt[((size_t)w * Hh + h) * Ee + k0 + kseg] = v;
    }
}

// ---------------------------------------------------------------------------
// Kernel 1: fused QKV projection, register-prefetch pipelined.
// grid (Mrows/32) = 512 (2 blocks/CU), block 256 (4 waves). Block: 32 rows x
// 384 cols (3 projections). Wave w owns col-frags F = 6w..6w+5 (F>>3 = proj,
// (F&7)*16 = col). Next k-tile's loads prefetched into named registers.
// V written transposed: Vtg[b][h][s]. Q pre-scaled by 1/sqrt(H).
// ---------------------------------------------------------------------------
__global__ __launch_bounds__(256, 2) void proj_kernel(
    const float* __restrict__ embds, const bf16* __restrict__ Wt,
    const float* __restrict__ bq, const float* __restrict__ bk,
    const float* __restrict__ bv,
    bf16* __restrict__ Qb, bf16* __restrict__ Kb, bf16* __restrict__ Vtg)
{
    __shared__ bf16 As[32][72];
    __shared__ bf16 Bs[3][128][72];

    const int t = threadIdx.x;
    const int wv = t >> 6, lane = t & 63, lo = lane & 15, hi = lane >> 4;
    const int m0 = blockIdx.x * 32;

    f32x4 acc[2][6];
    #pragma unroll
    for (int rg = 0; rg < 2; ++rg)
        #pragma unroll
        for (int f = 0; f < 6; ++f) acc[rg][f] = f32x4{0.f, 0.f, 0.f, 0.f};

    // A staging: thread owns row (t>>3), 8 contiguous k at (t&7)*8
    const int arow = t >> 3, acg = (t & 7) * 8;
    const float4* ag = (const float4*)(embds + (size_t)(m0 + arow) * Ee + acg);
    bf16* asl = &As[arow][acg];
    // B staging: rep r covers (w = r>>2, row = (r&3)*32 + (t>>3), k = (t&7)*8)
    const bf16* bg = Wt + (size_t)(t >> 3) * Ee + (t & 7) * 8;
    bf16* bsl = &Bs[0][t >> 3][(t & 7) * 8];

    float4 ar0, ar1;
    uint4 br0, br1, br2, br3, br4, br5, br6, br7, br8, br9, br10, br11;

#define BGOFF(r) ((size_t)((r) >> 2) * (Hh * Ee) + (size_t)((r) & 3) * (32 * Ee))
#define BLOFF(r) (((r) >> 2) * (128 * 72) + ((r) & 3) * (32 * 72))
#define ISSUE(K0) do {                                           \
        const float4* ap_ = ag + (K0) / 4;                       \
        ar0 = ap_[0]; ar1 = ap_[1];                              \
        const bf16* bp_ = bg + (K0);                             \
        br0  = *(const uint4*)(bp_ + BGOFF(0));                  \
        br1  = *(const uint4*)(bp_ + BGOFF(1));                  \
        br2  = *(const uint4*)(bp_ + BGOFF(2));                  \
        br3  = *(const uint4*)(bp_ + BGOFF(3));                  \
        br4  = *(const uint4*)(bp_ + BGOFF(4));                  \
        br5  = *(const uint4*)(bp_ + BGOFF(5));                  \
        br6  = *(const uint4*)(bp_ + BGOFF(6));                  \
        br7  = *(const uint4*)(bp_ + BGOFF(7));                  \
        br8  = *(const uint4*)(bp_ + BGOFF(8));                  \
        br9  = *(const uint4*)(bp_ + BGOFF(9));                  \
        br10 = *(const uint4*)(bp_ + BGOFF(10));                 \
        br11 = *(const uint4*)(bp_ + BGOFF(11));                 \
    } while (0)
#define CVT4(dst, v) do { bf16x4 o_;                             \
        o_[0] = (bf16)(v).x; o_[1] = (bf16)(v).y;                \
        o_[2] = (bf16)(v).z; o_[3] = (bf16)(v).w;                \
        *(bf16x4*)(dst) = o_; } while (0)

    ISSUE(0);
    for (int k0 = 0; k0 < Ee; k0 += 64) {
        __syncthreads();   // previous tile's LDS reads done
        CVT4(asl + 0, ar0); CVT4(asl + 4, ar1);
        *(uint4*)(bsl + BLOFF(0))  = br0;
        *(uint4*)(bsl + BLOFF(1))  = br1;
        *(uint4*)(bsl + BLOFF(2))  = br2;
        *(uint4*)(bsl + BLOFF(3))  = br3;
        *(uint4*)(bsl + BLOFF(4))  = br4;
        *(uint4*)(bsl + BLOFF(5))  = br5;
        *(uint4*)(bsl + BLOFF(6))  = br6;
        *(uint4*)(bsl + BLOFF(7))  = br7;
        *(uint4*)(bsl + BLOFF(8))  = br8;
        *(uint4*)(bsl + BLOFF(9))  = br9;
        *(uint4*)(bsl + BLOFF(10)) = br10;
        *(uint4*)(bsl + BLOFF(11)) = br11;
        if (k0 + 64 < Ee) ISSUE(k0 + 64);
        __syncthreads();
        __builtin_amdgcn_s_setprio(1);
        #pragma unroll
        for (int kk = 0; kk < 2; ++kk) {
            bf16x8 a0 = *(const bf16x8*)&As[lo][kk * 32 + hi * 8];
            bf16x8 a1 = *(const bf16x8*)&As[16 + lo][kk * 32 + hi * 8];
            #pragma unroll
            for (int f = 0; f < 6; ++f) {
                const int F = wv * 6 + f;
                const bf16* bp = &Bs[0][0][0] + (size_t)(F >> 3) * (128 * 72)
                               + (size_t)((F & 7) * 16 + lo) * 72 + kk * 32 + hi * 8;
                bf16x8 b = *(const bf16x8*)bp;
                acc[0][f] = MFMA16(a0, b, acc[0][f]);
                acc[1][f] = MFMA16(a1, b, acc[1][f]);
            }
        }
        __builtin_amdgcn_s_setprio(0);
    }
#undef ISSUE
#undef BGOFF
#undef BLOFF
#undef CVT4
    // epilogue: frag F -> proj/col; V transposed
    #pragma unroll
    for (int f = 0; f < 6; ++f) {
        const int F = wv * 6 + f;
        const int p = F >> 3;
        const int col = (F & 7) * 16 + lo;
        const float* bias = (p == 0) ? bq : (p == 1) ? bk : bv;
        float bvv = bias[col];
        if (p == 2) {
            const int mb = m0 >> 12, s0l = m0 & 4095;
            #pragma unroll
            for (int rg = 0; rg < 2; ++rg)
                #pragma unroll
                for (int i = 0; i < 4; ++i) {
                    int s = s0l + rg * 16 + hi * 4 + i;
                    Vtg[((size_t)mb * Hh + col) * Ss + s] = (bf16)(acc[rg][f][i] + bvv);
                }
        } else {
            bf16* dst = (p == 0) ? Qb : Kb;
            const float scale = (p == 0) ? 0.08838834764831843f : 1.0f;
            #pragma unroll
            for (int rg = 0; rg < 2; ++rg)
                #pragma unroll
                for (int i = 0; i < 4; ++i) {
                    int row = m0 + rg * 16 + hi * 4 + i;
                    dst[(size_t)row * Hh + col] = (bf16)((acc[rg][f][i] + bvv) * scale);
                }
        }
    }
}

// ---------------------------------------------------------------------------
// Kernel 2: split-KV causal flash attention, swapped QK^T, QBLK=128,
// UNIFORM chunks: grid (CH, B); block u covers qb with nchunks(qb) =
// ceil((2qb+2)/DIV) chunks of contiguous tiles (sizes differ by <=1).
// block 256 (4 waves x 32 q-rows, 2 q-groups each).
// ---------------------------------------------------------------------------
__global__ __launch_bounds__(256, 2) void attn_kernel(
    const bf16* __restrict__ Qb, const bf16* __restrict__ Kb,
    const bf16* __restrict__ Vtg,
    float* __restrict__ Opart, float* __restrict__ Mpart, float* __restrict__ Lpart,
    int DIV, int CH)
{
    __shared__ bf16 Ks[64][136];   // K tile, stride 272B
    __shared__ bf16 Vt[128][64];   // V^T tile, (h&7)-XOR swizzled 16B chunks
    __shared__ bf16 Ps[4][32][72]; // wave-private P[q][kv], 2 q-groups

    const int t = threadIdx.x;
    const int wv = t >> 6, lane = t & 63, lo = lane & 15, hi = lane >> 4;
    const int slot = blockIdx.x, b = blockIdx.y;

    // decode slot -> (qb, chunk u of nch)
    int u = slot, qb = 0, nch = 1;
    for (qb = 0; qb < NQB; ++qb) {
        nch = (2 * qb + 2 + DIV - 1) / DIV;
        if (u < nch) break;
        u -= nch;
    }
    const int ntiles = 2 * qb + 2;
    const int t0 = (u * ntiles) / nch;
    const int t1 = ((u + 1) * ntiles) / nch;

    const int q0 = qb * QB;
    const size_t base = (size_t)b * Ss * Hh;
    const size_t vbase = (size_t)b * Hh * Ss;

    // staging pointers (rep offsets compile-time)
    const bf16* kg = Kb + base + (size_t)(t >> 4) * Hh + (t & 15) * 8;
    const bf16* vg = Vtg + vbase + (size_t)(t >> 3) * Ss + (t & 7) * 8;
    bf16* ksl = &Ks[t >> 4][(t & 15) * 8];
    bf16* vsl = &Vt[t >> 3][((t & 7) * 8) ^ (((t >> 3) & 7) << 3)];

    // Q fragments: 2 q-groups x 4 k-steps
    bf16x8 qf[2][4];
    #pragma unroll
    for (int g = 0; g < 2; ++g)
        #pragma unroll
        for (int kk = 0; kk < 4; ++kk)
            qf[g][kk] = *(const bf16x8*)(
                Qb + base + (size_t)(q0 + wv * 32 + g * 16 + lo) * Hh + kk * 32 + hi * 8);

    f32x4 acc[2][8];
    #pragma unroll
    for (int g = 0; g < 2; ++g)
        #pragma unroll
        for (int f = 0; f < 8; ++f) acc[g][f] = f32x4{0.f, 0.f, 0.f, 0.f};
    float M_[2] = {-INFINITY, -INFINITY};
    float L_[2] = {0.f, 0.f};

    uint4 kr0, kr1, kr2, kr3, vr0, vr1, vr2, vr3;
#define ISSUE(T) do {                                            \
        const bf16* kp_ = kg + (size_t)(T) * (64 * Hh);          \
        kr0 = *(const uint4*)(kp_);                              \
        kr1 = *(const uint4*)(kp_ + 16 * Hh);                    \
        kr2 = *(const uint4*)(kp_ + 32 * Hh);                    \
        kr3 = *(const uint4*)(kp_ + 48 * Hh);                    \
        const bf16* vp_ = vg + (T) * 64;                         \
        vr0 = *(const uint4*)(vp_);                              \
        vr1 = *(const uint4*)(vp_ + 32 * Ss);                    \
        vr2 = *(const uint4*)(vp_ + 64 * Ss);                    \
        vr3 = *(const uint4*)(vp_ + 96 * Ss);                    \
    } while (0)

    ISSUE(t0);
    for (int tile = t0; tile < t1; ++tile) {
        __syncthreads();   // previous tile's LDS reads done
        *(uint4*)(ksl) = kr0;
        *(uint4*)(ksl + 16 * 136) = kr1;
        *(uint4*)(ksl + 32 * 136) = kr2;
        *(uint4*)(ksl + 48 * 136) = kr3;
        *(uint4*)(vsl) = vr0;
        *(uint4*)(vsl + 32 * 64) = vr1;
        *(uint4*)(vsl + 64 * 64) = vr2;
        *(uint4*)(vsl + 96 * 64) = vr3;
        if (tile + 1 < t1) ISSUE(tile + 1);
        __syncthreads();
        const int kv0 = tile * 64;

        // S^T = K Q^T per q-group: D[kv][q], kv = f*16+hi*4+i, q = lo
        f32x4 sv[2][4];
        #pragma unroll
        for (int g = 0; g < 2; ++g)
            #pragma unroll
            for (int f = 0; f < 4; ++f) sv[g][f] = f32x4{0.f, 0.f, 0.f, 0.f};
        __builtin_amdgcn_s_setprio(1);
        #pragma unroll
        for (int kk = 0; kk < 4; ++kk) {
            #pragma unroll
            for (int f = 0; f < 4; ++f) {
                bf16x8 kf = *(const bf16x8*)&Ks[f * 16 + lo][kk * 32 + hi * 8];
                sv[0][f] = MFMA16(kf, qf[0][kk], sv[0][f]);
                sv[1][f] = MFMA16(kf, qf[1][kk], sv[1][f]);
            }
        }
        __builtin_amdgcn_s_setprio(0);

        #pragma unroll
        for (int g = 0; g < 2; ++g) {
            const int qg0 = q0 + wv * 32 + g * 16;   // wave-uniform per g
            if (kv0 + 63 > qg0) {                    // masking needed
                int qg = qg0 + lo;
                #pragma unroll
                for (int f = 0; f < 4; ++f)
                    #pragma unroll
                    for (int i = 0; i < 4; ++i)
                        if (kv0 + f * 16 + hi * 4 + i > qg) sv[g][f][i] = -INFINITY;
            }
            // online softmax: lane owns 16 kv of row q=lo; tree + 2 shuffles
            float pm = -INFINITY;
            #pragma unroll
            for (int f = 0; f < 4; ++f)
                pm = fmaxf(pm, fmaxf(fmaxf(sv[g][f][0], sv[g][f][1]),
                                     fmaxf(sv[g][f][2], sv[g][f][3])));
            pm = fmaxf(pm, __shfl_xor(pm, 16));
            pm = fmaxf(pm, __shfl_xor(pm, 32));
            float nM = fmaxf(M_[g], pm);
            float nMs = fmaxf(nM, -1e37f);           // guard fully-masked group
            float scn = __expf(M_[g] - nMs);
            float rs = 0.f;
            #pragma unroll
            for (int f = 0; f < 4; ++f)
                #pragma unroll
                for (int i = 0; i < 4; ++i) {
                    float e = __expf(sv[g][f][i] - nMs);
                    sv[g][f][i] = e;
                    rs += e;
                }
            rs += __shfl_xor(rs, 16);
            rs += __shfl_xor(rs, 32);
            L_[g] = L_[g] * scn + rs;
            M_[g] = nM;
            // rescale O: acc row q' = hi*4+i needs scn of lane lo=q' (same hi)
            #pragma unroll
            for (int i = 0; i < 4; ++i) {
                float si = __shfl(scn, (lane & 48) + hi * 4 + i);
                #pragma unroll
                for (int f = 0; f < 8; ++f) acc[g][f][i] *= si;
            }
            // P -> wave-private LDS as P[q][kv]
            #pragma unroll
            for (int f = 0; f < 4; ++f)
                #pragma unroll
                for (int i = 0; i < 4; ++i)
                    Ps[wv][g * 16 + lo][f * 16 + hi * 4 + i] = (bf16)sv[g][f][i];
        }
        // O += P V
        __builtin_amdgcn_s_setprio(1);
        #pragma unroll
        for (int kk = 0; kk < 2; ++kk) {
            bf16x8 pa0 = *(const bf16x8*)&Ps[wv][lo][kk * 32 + hi * 8];
            bf16x8 pa1 = *(const bf16x8*)&Ps[wv][16 + lo][kk * 32 + hi * 8];
            #pragma unroll
            for (int f = 0; f < 8; ++f) {
                int row = f * 16 + lo;
                bf16x8 vf = *(const bf16x8*)&Vt[row][(kk * 32 + hi * 8) ^ ((row & 7) << 3)];
                acc[0][f] = MFMA16(pa0, vf, acc[0][f]);
                acc[1][f] = MFMA16(pa1, vf, acc[1][f]);
            }
        }
        __builtin_amdgcn_s_setprio(0);
    }
#undef ISSUE
    // write unnormalized partials
    const size_t pb = ((size_t)b * CH + slot) * QB;
    #pragma unroll
    for (int g = 0; g < 2; ++g)
        #pragma unroll
        for (int f = 0; f < 8; ++f)
            #pragma unroll
            for (int i = 0; i < 4; ++i) {
                int row = wv * 32 + g * 16 + hi * 4 + i;
                Opart[(pb + row) * 128 + f * 16 + lo] = acc[g][f][i];
            }
    if (hi == 0) {
        #pragma unroll
        for (int g = 0; g < 2; ++g) {
            Mpart[pb + wv * 32 + g * 16 + lo] = M_[g];
            Lpart[pb + wv * 32 + g * 16 + lo] = L_[g];
        }
    }
}

// ---------------------------------------------------------------------------
// Kernel 3: combine chunk partials (variable chunk counts).
// grid (NQB, B), block 256.
// ---------------------------------------------------------------------------
__global__ __launch_bounds__(256) void reduce_kernel(
    const float* __restrict__ Opart, const float* __restrict__ Mpart,
    const float* __restrict__ Lpart, float* __restrict__ out, int DIV, int CH)
{
    __shared__ float wexp[7][128];
    __shared__ float invL[128];
    const int qb = blockIdx.x, b = blockIdx.y, t = threadIdx.x;
    int pbase = 0, nact = 1;
    for (int j = 0; j <= qb; ++j) {
        int n = (2 * j + 2 + DIV - 1) / DIV;
        if (j == qb) { nact = n; break; }
        pbase += n;
    }
    const size_t pb = ((size_t)b * CH + pbase) * QB;
    if (t < 128) {
        float Mstar = -INFINITY;
        for (int c = 0; c < nact; ++c) Mstar = fmaxf(Mstar, Mpart[pb + c * QB + t]);
        float Ls = 0.f;
        for (int c = 0; c < nact; ++c) {
            float wc = __expf(Mpart[pb + c * QB + t] - Mstar);
            wexp[c][t] = wc;
            Ls += wc * Lpart[pb + c * QB + t];
        }
        invL[t] = 1.f / Ls;
    }
    __syncthreads();
    #pragma unroll
    for (int rep = 0; rep < 16; ++rep) {
        int idx = rep * 256 + t;
        int row = idx >> 5, c4 = (idx & 31) * 4;
        float ox = 0.f, oy = 0.f, oz = 0.f, ow = 0.f;
        for (int c = 0; c < nact; ++c) {
            float wc = wexp[c][row];
            float4 v = *(const float4*)(Opart + (pb + (size_t)c * QB + row) * 128 + c4);
            ox += wc * v.x; oy += wc * v.y; oz += wc * v.z; ow += wc * v.w;
        }
        float il = invL[row];
        float4 o = make_float4(ox * il, oy * il, oz * il, ow * il);
        *(float4*)(out + ((size_t)b * Ss + qb * QB + row) * 128 + c4) = o;
    }
}

extern "C" void kernel_launch(void* const* d_in, const int* in_sizes, int n_in,
                              void* d_out, int out_size, void* d_ws, size_t ws_size,
                              hipStream_t stream) {
    (void)in_sizes; (void)n_in; (void)out_size;
    const float* embds = (const float*)d_in[0];
    const float* Wq = (const float*)d_in[1];
    const float* bq = (const float*)d_in[2];
    const float* Wk = (const float*)d_in[3];
    const float* bk = (const float*)d_in[4];
    const float* Wv = (const float*)d_in[5];
    const float* bv = (const float*)d_in[6];

    char* ws = (char*)d_ws;
    size_t off = 0;
    bf16* Qb  = (bf16*)(ws + off); off += (size_t)Mrows * Hh * 2;
    bf16* Kb  = (bf16*)(ws + off); off += (size_t)Mrows * Hh * 2;
    bf16* Vtg = (bf16*)(ws + off); off += (size_t)Mrows * Hh * 2;
    bf16* Wt  = (bf16*)(ws + off); off += (size_t)3 * Hh * Ee * 2;

    auto chunks_for = [](int div) {
        int s = 0;
        for (int qb = 0; qb < NQB; ++qb) s += (2 * qb + 2 + div - 1) / div;
        return s;
    };
    int DIV = 10;
    int CH = chunks_for(DIV);   // 119
    if (off + (size_t)Bb * CH * QB * 128 * 4 + (size_t)Bb * CH * QB * 8 > ws_size) {
        DIV = 20;
        CH = chunks_for(DIV);   // 68
    }
    float* Opart = (float*)(ws + off);
    size_t osz = (size_t)Bb * CH * QB * 128 * 4;
    float* Mp = (float*)(ws + off + osz);
    float* Lp = Mp + (size_t)Bb * CH * QB;

    wprep_kernel<<<dim3(Ee / 16, 3), 256, 0, stream>>>(Wq, Wk, Wv, Wt);
    proj_kernel<<<dim3(Mrows / 32), 256, 0, stream>>>(embds, Wt, bq, bk, bv, Qb, Kb, Vtg);
    attn_kernel<<<dim3(CH, Bb), 256, 0, stream>>>(Qb, Kb, Vtg, Opart, Mp, Lp, DIV, CH);
    reduce_kernel<<<dim3(NQB, Bb), 256, 0, stream>>>(Opart, Mp, Lp, (float*)d_out, DIV, CH);
}

// Round 8
// 108.931 us; speedup vs baseline: 1.2687x; 1.0104x over previous
//
#include <hip/hip_runtime.h>

typedef __bf16 bf16;
typedef __attribute__((ext_vector_type(4))) bf16 bf16x4;
typedef __attribute__((ext_vector_type(8))) bf16 bf16x8;
typedef __attribute__((ext_vector_type(4))) float f32x4;

#define MFMA16(a, b, c) __builtin_amdgcn_mfma_f32_16x16x32_bf16(a, b, c, 0, 0, 0)

#define GLDS16(gsrc, ldst) __builtin_amdgcn_global_load_lds(                   \
    (const __attribute__((address_space(1))) unsigned int*)(gsrc),             \
    (__attribute__((address_space(3))) unsigned int*)(ldst), 16, 0, 0)

constexpr int Bb = 4, Ss = 4096, Ee = 1024, Hh = 128;
constexpr int Mrows = Bb * Ss;  // 16384
constexpr int QB = 128;         // attn q-block
constexpr int NQB = Ss / QB;    // 32

// ---------------------------------------------------------------------------
// Kernel 0: W prep. Transpose W [E,H] f32 -> Wt [3][H][E] bf16.
// grid (E/16, 3), block 256.
// ---------------------------------------------------------------------------
__global__ __launch_bounds__(256) void wprep_kernel(
    const float* __restrict__ Wq, const float* __restrict__ Wk,
    const float* __restrict__ Wv, bf16* __restrict__ Wt)
{
    __shared__ bf16 Sb[16][136];
    const int w = blockIdx.y;
    const float* W = (w == 0) ? Wq : (w == 1) ? Wk : Wv;
    const int k0 = blockIdx.x * 16;
    const int t = threadIdx.x;
    {
        int r = t >> 4, cg = (t & 15) * 8;
        const float4* src = (const float4*)(W + (size_t)(k0 + r) * Hh + cg);
        float4 v0 = src[0], v1 = src[1];
        bf16x4 o0, o1;
        o0[0] = (bf16)v0.x; o0[1] = (bf16)v0.y; o0[2] = (bf16)v0.z; o0[3] = (bf16)v0.w;
        o1[0] = (bf16)v1.x; o1[1] = (bf16)v1.y; o1[2] = (bf16)v1.z; o1[3] = (bf16)v1.w;
        *(bf16x4*)&Sb[r][cg] = o0;
        *(bf16x4*)&Sb[r][cg + 4] = o1;
    }
    __syncthreads();
    {
        int h = t >> 1, kseg = (t & 1) * 8;
        bf16x8 v;
        #pragma unroll
        for (int e = 0; e < 8; ++e) v[e] = Sb[kseg + e][h];
        *(bf16x8*)&Wt[((size_t)w * Hh + h) * Ee + k0 + kseg] = v;
    }
}

// ---------------------------------------------------------------------------
// Kernel 1: fused QKV projection, global_load_lds staged (m97 structure).
// grid (Mrows/32) = 512 (2 blocks/CU), block 256 (4 waves). Block: 32 rows x
// 384 cols. LDS single-buffered 56 KB: As 32x64 f32 (linear, chunk-swizzled
// content), Bs 384x64 bf16 (linear, chunk-swizzled content). Both-sides
// swizzle: gl_lds writes linear; SOURCE address pre-swizzled per lane; reads
// apply the same XOR. A converted f32->bf16 at fragment read.
// Wave w owns col-frags F = 6w..6w+5 (F>>3 = proj, (F&7)*16 = col).
// V written transposed: Vtg[b][h][s]. Q pre-scaled by 1/sqrt(H).
// ---------------------------------------------------------------------------
__global__ __launch_bounds__(256, 2) void proj_kernel(
    const float* __restrict__ embds, const bf16* __restrict__ Wt,
    const float* __restrict__ bq, const float* __restrict__ bk,
    const float* __restrict__ bv,
    bf16* __restrict__ Qb, bf16* __restrict__ Kb, bf16* __restrict__ Vtg)
{
    __shared__ float As[32][64];    // 8 KB,  row stride 256B, 16B chunks
    __shared__ bf16  Bs[384][64];   // 48 KB, row stride 128B, 16B chunks

    const int t = threadIdx.x;
    const int wv = t >> 6, lane = t & 63, lo = lane & 15, hi = lane >> 4;
    const int m0 = blockIdx.x * 32;

    f32x4 acc[2][6];
    #pragma unroll
    for (int rg = 0; rg < 2; ++rg)
        #pragma unroll
        for (int f = 0; f < 6; ++f) acc[rg][f] = f32x4{0.f, 0.f, 0.f, 0.f};

    // ---- staging address setup (per-lane source, wave-uniform dest) ----
    // A: segment s (1KB = 4 rows of 256B); wave wv owns s = 2wv, 2wv+1.
    //    lane l -> row = 4s + (l>>4), lds chunk = l&15,
    //    src chunk = (l&15) ^ (row&15)   [content swizzle]
    const int rowA0 = 8 * wv + (lane >> 4);          // s = 2wv
    const int rowA1 = 8 * wv + 4 + (lane >> 4);      // s = 2wv+1
    const float* ag0 = embds + (size_t)(m0 + rowA0) * Ee
                     + ((lane & 15) ^ (rowA0 & 15)) * 4;
    const float* ag1 = embds + (size_t)(m0 + rowA1) * Ee
                     + ((lane & 15) ^ (rowA1 & 15)) * 4;
    char* aD0 = (char*)&As[0][0] + (2 * wv) * 1024;
    char* aD1 = aD0 + 1024;
    // B: segment s (1KB = 8 rows of 128B); wave wv owns s = wv + 4j, j=0..11.
    //    lane l -> row = 8s + (l>>3), lds chunk = l&7,
    //    src chunk = (l&7) ^ (l>>3)        [row&7 == l>>3]
    const bf16* bg = Wt + (size_t)(8 * wv + (lane >> 3)) * Ee
                   + ((lane & 7) ^ (lane >> 3)) * 8;
    char* bD = (char*)&Bs[0][0] + wv * 1024;

    for (int k0 = 0; k0 < Ee; k0 += 64) {
        // stage (A first: HBM, longest latency)
        GLDS16(ag0 + k0, aD0);
        GLDS16(ag1 + k0, aD1);
        #pragma unroll
        for (int j = 0; j < 12; ++j)
            GLDS16(bg + (size_t)j * (32 * Ee) + k0, bD + j * 4096);
        __syncthreads();   // drains vmcnt -> staging visible

        __builtin_amdgcn_s_setprio(1);
        #pragma unroll
        for (int kk = 0; kk < 2; ++kk) {
            // A fragments: read swizzled f32 chunks, convert to bf16
            bf16x8 a0, a1;
            {
                const int row = lo, sw = row & 15;
                const char* ab = (const char*)&As[0][0] + row * 256;
                float4 q0 = *(const float4*)(ab + (((kk * 8 + 2 * hi)    ) ^ sw) * 16);
                float4 q1 = *(const float4*)(ab + (((kk * 8 + 2 * hi) | 1) ^ sw) * 16);
                a0[0] = (bf16)q0.x; a0[1] = (bf16)q0.y; a0[2] = (bf16)q0.z; a0[3] = (bf16)q0.w;
                a0[4] = (bf16)q1.x; a0[5] = (bf16)q1.y; a0[6] = (bf16)q1.z; a0[7] = (bf16)q1.w;
            }
            {
                const int row = 16 + lo, sw = row & 15;
                const char* ab = (const char*)&As[0][0] + row * 256;
                float4 q0 = *(const float4*)(ab + (((kk * 8 + 2 * hi)    ) ^ sw) * 16);
                float4 q1 = *(const float4*)(ab + (((kk * 8 + 2 * hi) | 1) ^ sw) * 16);
                a1[0] = (bf16)q0.x; a1[1] = (bf16)q0.y; a1[2] = (bf16)q0.z; a1[3] = (bf16)q0.w;
                a1[4] = (bf16)q1.x; a1[5] = (bf16)q1.y; a1[6] = (bf16)q1.z; a1[7] = (bf16)q1.w;
            }
            #pragma unroll
            for (int f = 0; f < 6; ++f) {
                const int F = wv * 6 + f;
                const int brow = F * 16 + lo;
                bf16x8 b = *(const bf16x8*)((const char*)&Bs[0][0] + brow * 128
                            + (((kk * 4 + hi) ^ (brow & 7)) * 16));
                acc[0][f] = MFMA16(a0, b, acc[0][f]);
                acc[1][f] = MFMA16(a1, b, acc[1][f]);
            }
        }
        __builtin_amdgcn_s_setprio(0);
        __syncthreads();   // all reads done before next stage overwrites
    }
    // epilogue: frag F -> proj/col; V transposed
    #pragma unroll
    for (int f = 0; f < 6; ++f) {
        const int F = wv * 6 + f;
        const int p = F >> 3;
        const int col = (F & 7) * 16 + lo;
        const float* bias = (p == 0) ? bq : (p == 1) ? bk : bv;
        float bvv = bias[col];
        if (p == 2) {
            const int mb = m0 >> 12, s0l = m0 & 4095;
            #pragma unroll
            for (int rg = 0; rg < 2; ++rg)
                #pragma unroll
                for (int i = 0; i < 4; ++i) {
                    int s = s0l + rg * 16 + hi * 4 + i;
                    Vtg[((size_t)mb * Hh + col) * Ss + s] = (bf16)(acc[rg][f][i] + bvv);
                }
        } else {
            bf16* dst = (p == 0) ? Qb : Kb;
            const float scale = (p == 0) ? 0.08838834764831843f : 1.0f;
            #pragma unroll
            for (int rg = 0; rg < 2; ++rg)
                #pragma unroll
                for (int i = 0; i < 4; ++i) {
                    int row = m0 + rg * 16 + hi * 4 + i;
                    dst[(size_t)row * Hh + col] = (bf16)((acc[rg][f][i] + bvv) * scale);
                }
        }
    }
}

// ---------------------------------------------------------------------------
// Kernel 2: split-KV causal flash attention, swapped QK^T, QBLK=128,
// UNIFORM chunks: grid (CH, B); block u covers qb with nchunks(qb) =
// ceil((2qb+2)/DIV) chunks of contiguous tiles (sizes differ by <=1).
// block 256 (4 waves x 32 q-rows, 2 q-groups each).
// ---------------------------------------------------------------------------
__global__ __launch_bounds__(256, 2) void attn_kernel(
    const bf16* __restrict__ Qb, const bf16* __restrict__ Kb,
    const bf16* __restrict__ Vtg,
    float* __restrict__ Opart, float* __restrict__ Mpart, float* __restrict__ Lpart,
    int DIV, int CH)
{
    __shared__ bf16 Ks[64][136];   // K tile, stride 272B
    __shared__ bf16 Vt[128][64];   // V^T tile, (h&7)-XOR swizzled 16B chunks
    __shared__ bf16 Ps[4][32][72]; // wave-private P[q][kv], 2 q-groups

    const int t = threadIdx.x;
    const int wv = t >> 6, lane = t & 63, lo = lane & 15, hi = lane >> 4;
    const int slot = blockIdx.x, b = blockIdx.y;

    // decode slot -> (qb, chunk u of nch)
    int u = slot, qb = 0, nch = 1;
    for (qb = 0; qb < NQB; ++qb) {
        nch = (2 * qb + 2 + DIV - 1) / DIV;
        if (u < nch) break;
        u -= nch;
    }
    const int ntiles = 2 * qb + 2;
    const int t0 = (u * ntiles) / nch;
    const int t1 = ((u + 1) * ntiles) / nch;

    const int q0 = qb * QB;
    const size_t base = (size_t)b * Ss * Hh;
    const size_t vbase = (size_t)b * Hh * Ss;

    // staging pointers (rep offsets compile-time)
    const bf16* kg = Kb + base + (size_t)(t >> 4) * Hh + (t & 15) * 8;
    const bf16* vg = Vtg + vbase + (size_t)(t >> 3) * Ss + (t & 7) * 8;
    bf16* ksl = &Ks[t >> 4][(t & 15) * 8];
    bf16* vsl = &Vt[t >> 3][((t & 7) * 8) ^ (((t >> 3) & 7) << 3)];

    // Q fragments: 2 q-groups x 4 k-steps
    bf16x8 qf[2][4];
    #pragma unroll
    for (int g = 0; g < 2; ++g)
        #pragma unroll
        for (int kk = 0; kk < 4; ++kk)
            qf[g][kk] = *(const bf16x8*)(
                Qb + base + (size_t)(q0 + wv * 32 + g * 16 + lo) * Hh + kk * 32 + hi * 8);

    f32x4 acc[2][8];
    #pragma unroll
    for (int g = 0; g < 2; ++g)
        #pragma unroll
        for (int f = 0; f < 8; ++f) acc[g][f] = f32x4{0.f, 0.f, 0.f, 0.f};
    float M_[2] = {-INFINITY, -INFINITY};
    float L_[2] = {0.f, 0.f};

    uint4 kr0, kr1, kr2, kr3, vr0, vr1, vr2, vr3;
#define ISSUE(T) do {                                            \
        const bf16* kp_ = kg + (size_t)(T) * (64 * Hh);          \
        kr0 = *(const uint4*)(kp_);                              \
        kr1 = *(const uint4*)(kp_ + 16 * Hh);                    \
        kr2 = *(const uint4*)(kp_ + 32 * Hh);                    \
        kr3 = *(const uint4*)(kp_ + 48 * Hh);                    \
        const bf16* vp_ = vg + (T) * 64;                         \
        vr0 = *(const uint4*)(vp_);                              \
        vr1 = *(const uint4*)(vp_ + 32 * Ss);                    \
        vr2 = *(const uint4*)(vp_ + 64 * Ss);                    \
        vr3 = *(const uint4*)(vp_ + 96 * Ss);                    \
    } while (0)

    ISSUE(t0);
    for (int tile = t0; tile < t1; ++tile) {
        __syncthreads();   // previous tile's LDS reads done
        *(uint4*)(ksl) = kr0;
        *(uint4*)(ksl + 16 * 136) = kr1;
        *(uint4*)(ksl + 32 * 136) = kr2;
        *(uint4*)(ksl + 48 * 136) = kr3;
        *(uint4*)(vsl) = vr0;
        *(uint4*)(vsl + 32 * 64) = vr1;
        *(uint4*)(vsl + 64 * 64) = vr2;
        *(uint4*)(vsl + 96 * 64) = vr3;
        if (tile + 1 < t1) ISSUE(tile + 1);
        __syncthreads();
        const int kv0 = tile * 64;

        // S^T = K Q^T per q-group: D[kv][q], kv = f*16+hi*4+i, q = lo
        f32x4 sv[2][4];
        #pragma unroll
        for (int g = 0; g < 2; ++g)
            #pragma unroll
            for (int f = 0; f < 4; ++f) sv[g][f] = f32x4{0.f, 0.f, 0.f, 0.f};
        __builtin_amdgcn_s_setprio(1);
        #pragma unroll
        for (int kk = 0; kk < 4; ++kk) {
            #pragma unroll
            for (int f = 0; f < 4; ++f) {
                bf16x8 kf = *(const bf16x8*)&Ks[f * 16 + lo][kk * 32 + hi * 8];
                sv[0][f] = MFMA16(kf, qf[0][kk], sv[0][f]);
                sv[1][f] = MFMA16(kf, qf[1][kk], sv[1][f]);
            }
        }
        __builtin_amdgcn_s_setprio(0);

        #pragma unroll
        for (int g = 0; g < 2; ++g) {
            const int qg0 = q0 + wv * 32 + g * 16;   // wave-uniform per g
            if (kv0 + 63 > qg0) {                    // masking needed
                int qg = qg0 + lo;
                #pragma unroll
                for (int f = 0; f < 4; ++f)
                    #pragma unroll
                    for (int i = 0; i < 4; ++i)
                        if (kv0 + f * 16 + hi * 4 + i > qg) sv[g][f][i] = -INFINITY;
            }
            // online softmax: lane owns 16 kv of row q=lo; tree + 2 shuffles
            float pm = -INFINITY;
            #pragma unroll
            for (int f = 0; f < 4; ++f)
                pm = fmaxf(pm, fmaxf(fmaxf(sv[g][f][0], sv[g][f][1]),
                                     fmaxf(sv[g][f][2], sv[g][f][3])));
            pm = fmaxf(pm, __shfl_xor(pm, 16));
            pm = fmaxf(pm, __shfl_xor(pm, 32));
            float nM = fmaxf(M_[g], pm);
            float nMs = fmaxf(nM, -1e37f);           // guard fully-masked group
            float scn = __expf(M_[g] - nMs);
            float rs = 0.f;
            #pragma unroll
            for (int f = 0; f < 4; ++f)
                #pragma unroll
                for (int i = 0; i < 4; ++i) {
                    float e = __expf(sv[g][f][i] - nMs);
                    sv[g][f][i] = e;
                    rs += e;
                }
            rs += __shfl_xor(rs, 16);
            rs += __shfl_xor(rs, 32);
            L_[g] = L_[g] * scn + rs;
            M_[g] = nM;
            // rescale O: acc row q' = hi*4+i needs scn of lane lo=q' (same hi)
            #pragma unroll
            for (int i = 0; i < 4; ++i) {
                float si = __shfl(scn, (lane & 48) + hi * 4 + i);
                #pragma unroll
                for (int f = 0; f < 8; ++f) acc[g][f][i] *= si;
            }
            // P -> wave-private LDS as P[q][kv]
            #pragma unroll
            for (int f = 0; f < 4; ++f)
                #pragma unroll
                for (int i = 0; i < 4; ++i)
                    Ps[wv][g * 16 + lo][f * 16 + hi * 4 + i] = (bf16)sv[g][f][i];
        }
        // O += P V
        __builtin_amdgcn_s_setprio(1);
        #pragma unroll
        for (int kk = 0; kk < 2; ++kk) {
            bf16x8 pa0 = *(const bf16x8*)&Ps[wv][lo][kk * 32 + hi * 8];
            bf16x8 pa1 = *(const bf16x8*)&Ps[wv][16 + lo][kk * 32 + hi * 8];
            #pragma unroll
            for (int f = 0; f < 8; ++f) {
                int row = f * 16 + lo;
                bf16x8 vf = *(const bf16x8*)&Vt[row][(kk * 32 + hi * 8) ^ ((row & 7) << 3)];
                acc[0][f] = MFMA16(pa0, vf, acc[0][f]);
                acc[1][f] = MFMA16(pa1, vf, acc[1][f]);
            }
        }
        __builtin_amdgcn_s_setprio(0);
    }
#undef ISSUE
    // write unnormalized partials
    const size_t pb = ((size_t)b * CH + slot) * QB;
    #pragma unroll
    for (int g = 0; g < 2; ++g)
        #pragma unroll
        for (int f = 0; f < 8; ++f)
            #pragma unroll
            for (int i = 0; i < 4; ++i) {
                int row = wv * 32 + g * 16 + hi * 4 + i;
                Opart[(pb + row) * 128 + f * 16 + lo] = acc[g][f][i];
            }
    if (hi == 0) {
        #pragma unroll
        for (int g = 0; g < 2; ++g) {
            Mpart[pb + wv * 32 + g * 16 + lo] = M_[g];
            Lpart[pb + wv * 32 + g * 16 + lo] = L_[g];
        }
    }
}

// ---------------------------------------------------------------------------
// Kernel 3: combine chunk partials (variable chunk counts).
// grid (NQB, B), block 256.
// ---------------------------------------------------------------------------
__global__ __launch_bounds__(256) void reduce_kernel(
    const float* __restrict__ Opart, const float* __restrict__ Mpart,
    const float* __restrict__ Lpart, float* __restrict__ out, int DIV, int CH)
{
    __shared__ float wexp[7][128];
    __shared__ float invL[128];
    const int qb = blockIdx.x, b = blockIdx.y, t = threadIdx.x;
    int pbase = 0, nact = 1;
    for (int j = 0; j <= qb; ++j) {
        int n = (2 * j + 2 + DIV - 1) / DIV;
        if (j == qb) { nact = n; break; }
        pbase += n;
    }
    const size_t pb = ((size_t)b * CH + pbase) * QB;
    if (t < 128) {
        float Mstar = -INFINITY;
        for (int c = 0; c < nact; ++c) Mstar = fmaxf(Mstar, Mpart[pb + c * QB + t]);
        float Ls = 0.f;
        for (int c = 0; c < nact; ++c) {
            float wc = __expf(Mpart[pb + c * QB + t] - Mstar);
            wexp[c][t] = wc;
            Ls += wc * Lpart[pb + c * QB + t];
        }
        invL[t] = 1.f / Ls;
    }
    __syncthreads();
    #pragma unroll
    for (int rep = 0; rep < 16; ++rep) {
        int idx = rep * 256 + t;
        int row = idx >> 5, c4 = (idx & 31) * 4;
        float ox = 0.f, oy = 0.f, oz = 0.f, ow = 0.f;
        for (int c = 0; c < nact; ++c) {
            float wc = wexp[c][row];
            float4 v = *(const float4*)(Opart + (pb + (size_t)c * QB + row) * 128 + c4);
            ox += wc * v.x; oy += wc * v.y; oz += wc * v.z; ow += wc * v.w;
        }
        float il = invL[row];
        float4 o = make_float4(ox * il, oy * il, oz * il, ow * il);
        *(float4*)(out + ((size_t)b * Ss + qb * QB + row) * 128 + c4) = o;
    }
}

extern "C" void kernel_launch(void* const* d_in, const int* in_sizes, int n_in,
                              void* d_out, int out_size, void* d_ws, size_t ws_size,
                              hipStream_t stream) {
    (void)in_sizes; (void)n_in; (void)out_size;
    const float* embds = (const float*)d_in[0];
    const float* Wq = (const float*)d_in[1];
    const float* bq = (const float*)d_in[2];
    const float* Wk = (const float*)d_in[3];
    const float* bk = (const float*)d_in[4];
    const float* Wv = (const float*)d_in[5];
    const float* bv = (const float*)d_in[6];

    char* ws = (char*)d_ws;
    size_t off = 0;
    bf16* Qb  = (bf16*)(ws + off); off += (size_t)Mrows * Hh * 2;
    bf16* Kb  = (bf16*)(ws + off); off += (size_t)Mrows * Hh * 2;
    bf16* Vtg = (bf16*)(ws + off); off += (size_t)Mrows * Hh * 2;
    bf16* Wt  = (bf16*)(ws + off); off += (size_t)3 * Hh * Ee * 2;

    auto chunks_for = [](int div) {
        int s = 0;
        for (int qb = 0; qb < NQB; ++qb) s += (2 * qb + 2 + div - 1) / div;
        return s;
    };
    int DIV = 10;
    int CH = chunks_for(DIV);   // 119
    if (off + (size_t)Bb * CH * QB * 128 * 4 + (size_t)Bb * CH * QB * 8 > ws_size) {
        DIV = 20;
        CH = chunks_for(DIV);   // 68
    }
    float* Opart = (float*)(ws + off);
    size_t osz = (size_t)Bb * CH * QB * 128 * 4;
    float* Mp = (float*)(ws + off + osz);
    float* Lp = Mp + (size_t)Bb * CH * QB;

    wprep_kernel<<<dim3(Ee / 16, 3), 256, 0, stream>>>(Wq, Wk, Wv, Wt);
    proj_kernel<<<dim3(Mrows / 32), 256, 0, stream>>>(embds, Wt, bq, bk, bv, Qb, Kb, Vtg);
    attn_kernel<<<dim3(CH, Bb), 256, 0, stream>>>(Qb, Kb, Vtg, Opart, Mp, Lp, DIV, CH);
    reduce_kernel<<<dim3(NQB, Bb), 256, 0, stream>>>(Opart, Mp, Lp, (float*)d_out, DIV, CH);
}